// Round 6
// baseline (3239.423 us; speedup 1.0000x reference)
//
#include <hip/hip_runtime.h>

typedef _Float16 f16;
typedef __attribute__((ext_vector_type(4))) _Float16 f16x4;
typedef __attribute__((ext_vector_type(8))) _Float16 f16x8;
typedef __attribute__((ext_vector_type(4))) float f32x4;

#define NT 512

// ---------------------------------------------------------------------------
// GEMM1: xW[t][g][b][j] = sum_k x[b,t,k] * W_ih[g*1024+j, k]   (fp16 out)
// ---------------------------------------------------------------------------
__global__ __launch_bounds__(256) void gemm_xw(
    const float* __restrict__ x,    // [32768, 1024] rows = b*512+t
    const float* __restrict__ Wih,  // [3072, 1024]
    f16* __restrict__ xw)           // [((t*3+g)*64+b)*1024 + j]
{
  const int nblk = blockIdx.x;   // 0..23
  const int mblk = blockIdx.y;   // 0..255
  const int tid  = threadIdx.x;
  const int lane = tid & 63;
  const int wv   = tid >> 6;
  const int wm   = wv >> 1;      // 0..1
  const int wn   = wv & 1;       // 0..1

  __shared__ f16 sA[128 * 40];
  __shared__ f16 sB[128 * 40];

  const int m0 = mblk * 128;
  const int n0 = nblk * 128;

  const int srow = tid >> 3;         // 0..31
  const int scol = (tid & 7) * 4;    // 0..28

  const int lr = lane & 15;
  const int lk = (lane >> 4) * 8;

  f32x4 acc[4][4];
#pragma unroll
  for (int i = 0; i < 4; ++i)
#pragma unroll
    for (int jj = 0; jj < 4; ++jj) acc[i][jj] = (f32x4){0.f, 0.f, 0.f, 0.f};

  for (int kb = 0; kb < 32; ++kb) {
    const int k0 = kb * 32;
#pragma unroll
    for (int rb = 0; rb < 4; ++rb) {
      const int row = srow + rb * 32;
      float4 va = *(const float4*)&x[(size_t)(m0 + row) * 1024 + k0 + scol];
      f16x4 ha; ha[0] = va.x; ha[1] = va.y; ha[2] = va.z; ha[3] = va.w;
      *(f16x4*)&sA[row * 40 + scol] = ha;
      float4 vb = *(const float4*)&Wih[(size_t)(n0 + row) * 1024 + k0 + scol];
      f16x4 hb; hb[0] = vb.x; hb[1] = vb.y; hb[2] = vb.z; hb[3] = vb.w;
      *(f16x4*)&sB[row * 40 + scol] = hb;
    }
    __syncthreads();
    f16x8 af[4], bfr[4];
#pragma unroll
    for (int mi = 0; mi < 4; ++mi)
      af[mi] = *(const f16x8*)&sA[(wm * 64 + mi * 16 + lr) * 40 + lk];
#pragma unroll
    for (int ni = 0; ni < 4; ++ni)
      bfr[ni] = *(const f16x8*)&sB[(wn * 64 + ni * 16 + lr) * 40 + lk];
#pragma unroll
    for (int mi = 0; mi < 4; ++mi)
#pragma unroll
      for (int ni = 0; ni < 4; ++ni)
        acc[mi][ni] = __builtin_amdgcn_mfma_f32_16x16x32_f16(af[mi], bfr[ni], acc[mi][ni], 0, 0, 0);
    __syncthreads();
  }

  const int b  = mblk >> 2;
  const int t0 = (mblk & 3) * 128;
  const int g  = nblk >> 3;
  const int j0 = (nblk & 7) * 128;
#pragma unroll
  for (int mi = 0; mi < 4; ++mi) {
#pragma unroll
    for (int r = 0; r < 4; ++r) {
      const int ri = wm * 64 + mi * 16 + (lane >> 4) * 4 + r;
      const int t  = t0 + ri;
#pragma unroll
      for (int ni = 0; ni < 4; ++ni) {
        const int j = j0 + wn * 64 + ni * 16 + lr;
        xw[(size_t)((t * 3 + g) * 64 + b) * 1024 + j] = (f16)acc[mi][ni][r];
      }
    }
  }
}

// ---------------------------------------------------------------------------
// Recurrence. 64 unit-chunks x 4 batch groups, 3 waves/WG:
//   wave0: fabric poll (sole poller) -> LDS token -> stage chunks 0..63,
//          r-gate MFMA.
//   wave1: LDS-token spin -> stage chunks 64..127; z-gate MFMA; out(t-1)
//          nt-stores under counted vmcnt(1) (off all wait paths).
//   wave2: n-gate MFMA + combine; release = LDS-bounce -> ONE dwordx4
//          sc0sc1 h-store -> vmcnt(0) -> flag; then xw(t+1) prefetch.
// hstage rows padded to 1040 f16 + chunk XOR swizzle (bank-conflict fix).
// ---------------------------------------------------------------------------
__device__ __forceinline__ float sigm(float v) { return 1.f / (1.f + __expf(-v)); }
__device__ __forceinline__ float tanh_fast(float v) { return 1.f - 2.f / (1.f + __expf(2.f * v)); }

__global__ __launch_bounds__(192, 1) void recur(
    const f16* __restrict__ xw,      // [((t*3+g)*64+b)*1024 + j]
    const float* __restrict__ mixp,  // [64*512]
    const float* __restrict__ Whh,   // [3072, 1024]
    const float* __restrict__ bih,   // [3072]
    const float* __restrict__ bhh,   // [3072]
    float* __restrict__ out,         // h: [64*512*1024], then o: [64*1024]
    f16* __restrict__ hbuf,          // [2][64*1024]
    int* __restrict__ flags)         // [4][64], memset 0 before launch
{
  const int c = blockIdx.x;          // 0..63 unit chunk
  const int m = blockIdx.y;          // 0..3  batch group
  const int tid = threadIdx.x;
  const int w = tid >> 6;            // 0,1 stagers; 2 producer
  const int lane = tid & 63;
  const int lr = lane & 15;
  const int q  = lane >> 4;          // 0..3
  const int lk = q * 8;
  const int rrow = q * 4;
  const int m0 = m * 16;
  const int j  = c * 16 + lr;        // hidden unit
  const int grow = w * 1024 + j;     // W_hh row (gate = w)

  __shared__ float smix[16][512];      // 32 KB
  __shared__ f16 hstage[16 * 1040];    // 33.3 KB, padded + XOR swizzle
  __shared__ float ldsRZ[2][16][16];   // 2 KB
  __shared__ f16 ldsH[16 * 16];        // 512 B
  __shared__ float ldsO[2][16 * 16];   // 2 KB, parity double-buffer
  __shared__ int ldsTok;

  if (tid == 0) ldsTok = 0;
  for (int i = tid; i < 2048; i += 192) {
    const int row = i >> 7;
    const int col = (i & 127) * 4;
    *(float4*)&smix[row][col] = *(const float4*)&mixp[(m0 + row) * 512 + col];
  }

  // W_hh rows as fp16 B-fragments, VGPR-resident.
  f16x8 bf[32];
#pragma unroll
  for (int kc = 0; kc < 32; ++kc) {
    const float* s = &Whh[(size_t)grow * 1024 + kc * 32 + lk];
    float4 v0 = *(const float4*)(s);
    float4 v1 = *(const float4*)(s + 4);
    f16x8 hv;
    hv[0] = v0.x; hv[1] = v0.y; hv[2] = v0.z; hv[3] = v0.w;
    hv[4] = v1.x; hv[5] = v1.y; hv[6] = v1.z; hv[7] = v1.w;
    bf[kc] = hv;
  }
  const float bhw = bhh[grow];
  float bi0 = 0.f, bi1 = 0.f, bi2 = 0.f;
  if (w == 2) { bi0 = bih[j]; bi1 = bih[1024 + j]; bi2 = bih[2048 + j]; }

  float hprev[4] = {0.f, 0.f, 0.f, 0.f};
  int* myflags = &flags[m * 64];

  __syncthreads();  // smix/ldsTok ready

  // producer prologue: xW(0) + mix(0)
  float xr[4], xz[4], xn[4], mt[4];
  if (w == 2) {
#pragma unroll
    for (int r = 0; r < 4; ++r) {
      const int b = m0 + rrow + r;
      xr[r] = (float)__builtin_nontemporal_load(&xw[(size_t)(0 * 64 + b) * 1024 + j]);
      xz[r] = (float)__builtin_nontemporal_load(&xw[(size_t)(1 * 64 + b) * 1024 + j]);
      xn[r] = (float)__builtin_nontemporal_load(&xw[(size_t)(2 * 64 + b) * 1024 + j]);
      mt[r] = smix[rrow + r][0];
    }
  }

  for (int t = 0; t < NT; ++t) {
    if (t > 0 && w < 2) {
      if (w == 0) {
        // sole fabric poller: all 64 flags of this group
        while (__hip_atomic_load(&myflags[lane], __ATOMIC_RELAXED,
                                 __HIP_MEMORY_SCOPE_AGENT) < t) {}
        __builtin_amdgcn_sched_barrier(0);
        *(volatile int*)&ldsTok = t;
      } else {
        while (*(volatile int*)&ldsTok < t) {}
      }
      // stage our 64-chunk half (coalesced 512B x2 per instr), LLC-direct
      const f16* hsrc = hbuf + (size_t)(t & 1) * (64 * 1024) + (size_t)m0 * 1024;
      f16x8 v[16];
#pragma unroll
      for (int i = 0; i < 16; ++i) {
        const int row = 2 * (i & 7) + (lane >> 5);
        const int ch  = w * 64 + (i >> 3) * 32 + (lane & 31);
        const f16* p = hsrc + row * 1024 + ch * 8;
        asm volatile("global_load_dwordx4 %0, %1, off sc0 sc1"
                     : "=v"(v[i]) : "v"(p));
      }
      if (w == 1) {
        // out(t-1): full-line nt float4, ack hidden under MFMA phase
        f32x4 ov = *(const f32x4*)&ldsO[(t - 1) & 1][(lane >> 2) * 16 + (lane & 3) * 4];
        float* pa = out + ((size_t)(m0 + (lane >> 2)) * 512 + (t - 1)) * 1024 + c * 16 + (lane & 3) * 4;
        asm volatile("global_store_dwordx4 %0, %1, off nt"
                     :: "v"(pa), "v"(ov) : "memory");
        asm volatile("s_waitcnt vmcnt(1)" ::: "memory");  // 16 loads done, store may fly
      } else {
        asm volatile("s_waitcnt vmcnt(0)" ::: "memory");
      }
#pragma unroll
      for (int i = 0; i < 16; ++i) {
        asm volatile("" : "+v"(v[i]));
        const int row = 2 * (i & 7) + (lane >> 5);
        const int ch  = w * 64 + (i >> 3) * 32 + (lane & 31);
        *(f16x8*)&hstage[row * 1040 + ((ch ^ (row & 7)) * 8)] = v[i];
      }
    }
    __syncthreads();  // B_stage
    f32x4 acc = {0.f, 0.f, 0.f, 0.f};
    if (t > 0) {
      f32x4 a0 = {0,0,0,0}, a1 = {0,0,0,0}, a2 = {0,0,0,0}, a3 = {0,0,0,0};
#pragma unroll
      for (int kc = 0; kc < 32; kc += 4) {
        f16x8 h0 = *(const f16x8*)&hstage[lr * 1040 + ((((kc + 0) * 4 + q) ^ (lr & 7)) * 8)];
        f16x8 h1 = *(const f16x8*)&hstage[lr * 1040 + ((((kc + 1) * 4 + q) ^ (lr & 7)) * 8)];
        f16x8 h2 = *(const f16x8*)&hstage[lr * 1040 + ((((kc + 2) * 4 + q) ^ (lr & 7)) * 8)];
        f16x8 h3 = *(const f16x8*)&hstage[lr * 1040 + ((((kc + 3) * 4 + q) ^ (lr & 7)) * 8)];
        a0 = __builtin_amdgcn_mfma_f32_16x16x32_f16(h0, bf[kc + 0], a0, 0, 0, 0);
        a1 = __builtin_amdgcn_mfma_f32_16x16x32_f16(h1, bf[kc + 1], a1, 0, 0, 0);
        a2 = __builtin_amdgcn_mfma_f32_16x16x32_f16(h2, bf[kc + 2], a2, 0, 0, 0);
        a3 = __builtin_amdgcn_mfma_f32_16x16x32_f16(h3, bf[kc + 3], a3, 0, 0, 0);
      }
      acc = (a0 + a1) + (a2 + a3);
    }
    if (w < 2) {
#pragma unroll
      for (int r = 0; r < 4; ++r) ldsRZ[w][rrow + r][lr] = acc[r] + bhw;
    }
    __syncthreads();  // B_rz
    if (w == 2) {
      float* lo = &ldsO[t & 1][0];
#pragma unroll
      for (int r = 0; r < 4; ++r) {
        const int row = rrow + r;
        const float hr = ldsRZ[0][row][lr];
        const float hz = ldsRZ[1][row][lr];
        const float hn = acc[r] + bhw;
        const float rg = sigm(xr[r] + bi0 + hr);
        const float zg = sigm(xz[r] + bi1 + hz);
        const float ng = tanh_fast(xn[r] + bi2 + rg * hn);
        const float hnew = (1.f - zg) * ng + zg * hprev[r];
        const float hm = mt[r] * hnew + (1.f - mt[r]) * hprev[r];
        hprev[r] = hm;
        ldsH[row * 16 + lr] = (f16)hm;
        lo[row * 16 + lr] = hm;
      }
    }
    __syncthreads();  // B4: ldsH/ldsO published
    if (w == 2) {
      if (lane < 32) {
        f16x8 hv = *(const f16x8*)&ldsH[(lane >> 1) * 16 + (lane & 1) * 8];
        f16* p = hbuf + (size_t)((t + 1) & 1) * (64 * 1024)
               + (size_t)(m0 + (lane >> 1)) * 1024 + c * 16 + (lane & 1) * 8;
        asm volatile("global_store_dwordx4 %0, %1, off sc0 sc1"
                     :: "v"(p), "v"(hv) : "memory");
      }
      asm volatile("s_waitcnt vmcnt(0)" ::: "memory");
      if (lane == 0)
        __hip_atomic_store(&myflags[c], t + 1, __ATOMIC_RELAXED, __HIP_MEMORY_SCOPE_AGENT);
      // off-path: next-step xW prefetch
      const int tn = (t + 1 < NT) ? t + 1 : NT - 1;
#pragma unroll
      for (int r = 0; r < 4; ++r) {
        const int b = m0 + rrow + r;
        xr[r] = (float)__builtin_nontemporal_load(&xw[(size_t)((tn * 3 + 0) * 64 + b) * 1024 + j]);
        xz[r] = (float)__builtin_nontemporal_load(&xw[(size_t)((tn * 3 + 1) * 64 + b) * 1024 + j]);
        xn[r] = (float)__builtin_nontemporal_load(&xw[(size_t)((tn * 3 + 2) * 64 + b) * 1024 + j]);
        mt[r] = smix[rrow + r][tn];
      }
    }
  }
  // epilogue: out(511) + final o, from ldsO[511&1 == 1]
  if (w == 1) {
    const int row = lane >> 2, part = lane & 3;
    f32x4 ov = *(const f32x4*)&ldsO[1][row * 16 + part * 4];
    float* p1 = out + ((size_t)(m0 + row) * 512 + 511) * 1024 + c * 16 + part * 4;
    float* p2 = out + (size_t)64 * 512 * 1024 + (size_t)(m0 + row) * 1024 + c * 16 + part * 4;
    __builtin_nontemporal_store(ov, (f32x4*)p1);
    __builtin_nontemporal_store(ov, (f32x4*)p2);
  }
}

// ---------------------------------------------------------------------------
extern "C" void kernel_launch(void* const* d_in, const int* in_sizes, int n_in,
                              void* d_out, int out_size, void* d_ws, size_t ws_size,
                              hipStream_t stream) {
  const float* x    = (const float*)d_in[0];
  const float* mixp = (const float*)d_in[1];
  const float* Wih  = (const float*)d_in[2];
  const float* Whh  = (const float*)d_in[3];
  const float* bih  = (const float*)d_in[4];
  const float* bhh  = (const float*)d_in[5];
  float* out = (float*)d_out;

  const size_t XW_BYTES = (size_t)512 * 3 * 64 * 1024 * sizeof(f16);  // 201326592
  f16* xw    = (f16*)d_ws;
  f16* hbuf  = (f16*)((char*)d_ws + XW_BYTES);
  int* flags = (int*)((char*)d_ws + XW_BYTES + (size_t)2 * 64 * 1024 * sizeof(f16));

  hipMemsetAsync(flags, 0, 4 * 64 * sizeof(int), stream);

  dim3 gg(24, 256);
  gemm_xw<<<gg, 256, 0, stream>>>(x, Wih, xw);

  dim3 gr(64, 4);
  recur<<<gr, 192, 0, stream>>>(xw, mixp, Whh, bih, bhh, out, hbuf, flags);
}

// Round 7
// 2366.459 us; speedup vs baseline: 1.3689x; 1.3689x over previous
//
#include <hip/hip_runtime.h>

typedef _Float16 f16;
typedef __attribute__((ext_vector_type(4))) _Float16 f16x4;
typedef __attribute__((ext_vector_type(8))) _Float16 f16x8;
typedef __attribute__((ext_vector_type(4))) float f32x4;

#define NT 512

// ---------------------------------------------------------------------------
// GEMM1: xW[t][g][b][j] = sum_k x[b,t,k] * W_ih[g*1024+j, k]   (fp16 out)
// ---------------------------------------------------------------------------
__global__ __launch_bounds__(256) void gemm_xw(
    const float* __restrict__ x,    // [32768, 1024] rows = b*512+t
    const float* __restrict__ Wih,  // [3072, 1024]
    f16* __restrict__ xw)           // [((t*3+g)*64+b)*1024 + j]
{
  const int nblk = blockIdx.x;   // 0..23
  const int mblk = blockIdx.y;   // 0..255
  const int tid  = threadIdx.x;
  const int lane = tid & 63;
  const int wv   = tid >> 6;
  const int wm   = wv >> 1;      // 0..1
  const int wn   = wv & 1;       // 0..1

  __shared__ f16 sA[128 * 40];
  __shared__ f16 sB[128 * 40];

  const int m0 = mblk * 128;
  const int n0 = nblk * 128;

  const int srow = tid >> 3;         // 0..31
  const int scol = (tid & 7) * 4;    // 0..28

  const int lr = lane & 15;
  const int lk = (lane >> 4) * 8;

  f32x4 acc[4][4];
#pragma unroll
  for (int i = 0; i < 4; ++i)
#pragma unroll
    for (int jj = 0; jj < 4; ++jj) acc[i][jj] = (f32x4){0.f, 0.f, 0.f, 0.f};

  for (int kb = 0; kb < 32; ++kb) {
    const int k0 = kb * 32;
#pragma unroll
    for (int rb = 0; rb < 4; ++rb) {
      const int row = srow + rb * 32;
      float4 va = *(const float4*)&x[(size_t)(m0 + row) * 1024 + k0 + scol];
      f16x4 ha; ha[0] = va.x; ha[1] = va.y; ha[2] = va.z; ha[3] = va.w;
      *(f16x4*)&sA[row * 40 + scol] = ha;
      float4 vb = *(const float4*)&Wih[(size_t)(n0 + row) * 1024 + k0 + scol];
      f16x4 hb; hb[0] = vb.x; hb[1] = vb.y; hb[2] = vb.z; hb[3] = vb.w;
      *(f16x4*)&sB[row * 40 + scol] = hb;
    }
    __syncthreads();
    f16x8 af[4], bfr[4];
#pragma unroll
    for (int mi = 0; mi < 4; ++mi)
      af[mi] = *(const f16x8*)&sA[(wm * 64 + mi * 16 + lr) * 40 + lk];
#pragma unroll
    for (int ni = 0; ni < 4; ++ni)
      bfr[ni] = *(const f16x8*)&sB[(wn * 64 + ni * 16 + lr) * 40 + lk];
#pragma unroll
    for (int mi = 0; mi < 4; ++mi)
#pragma unroll
      for (int ni = 0; ni < 4; ++ni)
        acc[mi][ni] = __builtin_amdgcn_mfma_f32_16x16x32_f16(af[mi], bfr[ni], acc[mi][ni], 0, 0, 0);
    __syncthreads();
  }

  const int b  = mblk >> 2;
  const int t0 = (mblk & 3) * 128;
  const int g  = nblk >> 3;
  const int j0 = (nblk & 7) * 128;
#pragma unroll
  for (int mi = 0; mi < 4; ++mi) {
#pragma unroll
    for (int r = 0; r < 4; ++r) {
      const int ri = wm * 64 + mi * 16 + (lane >> 4) * 4 + r;
      const int t  = t0 + ri;
#pragma unroll
      for (int ni = 0; ni < 4; ++ni) {
        const int j = j0 + wn * 64 + ni * 16 + lr;
        xw[(size_t)((t * 3 + g) * 64 + b) * 1024 + j] = (f16)acc[mi][ni][r];
      }
    }
  }
}

// ---------------------------------------------------------------------------
// Recurrence. 64 unit-chunks x 4 batch groups, 3 waves/WG.
// Hub-tree sync: WG c==0's wave0 is the SOLE poller of the 64 producer
// flags; it publishes a per-group epoch word (own cacheline). All other
// WGs poll only the epoch line (read-only, 1 writer). This removes the
// poll-storm contention on the producer flag stores.
// wave0/1: epoch poll -> stage h half (sc0sc1) -> MFMA (r/z gate).
// wave1 additionally: out(t-1) nt-store issued after stage loads, vmcnt(1).
// wave2: n-gate MFMA, combine, ldsH bounce (same-wave, no barrier),
//        ONE dwordx4 sc0sc1 h-store -> vmcnt(0)+lgkmcnt(0) -> flag ->
//        xw(t+1) prefetch. 2 barriers/step.
// ---------------------------------------------------------------------------
__device__ __forceinline__ float sigm(float v) { return 1.f / (1.f + __expf(-v)); }
__device__ __forceinline__ float tanh_fast(float v) { return 1.f - 2.f / (1.f + __expf(2.f * v)); }

__global__ __launch_bounds__(192, 1) void recur(
    const f16* __restrict__ xw,      // [((t*3+g)*64+b)*1024 + j]
    const float* __restrict__ mixp,  // [64*512]
    const float* __restrict__ Whh,   // [3072, 1024]
    const float* __restrict__ bih,   // [3072]
    const float* __restrict__ bhh,   // [3072]
    float* __restrict__ out,         // h: [64*512*1024], then o: [64*1024]
    f16* __restrict__ hbuf,          // [2][64*1024]
    int* __restrict__ flags)         // [4][64] prod flags + epoch @ 512+m*32
{
  const int c = blockIdx.x;          // 0..63 unit chunk
  const int m = blockIdx.y;          // 0..3  batch group
  const int tid = threadIdx.x;
  const int w = tid >> 6;            // 0,1 stagers; 2 producer
  const int lane = tid & 63;
  const int lr = lane & 15;
  const int q  = lane >> 4;          // 0..3
  const int lk = q * 8;
  const int rrow = q * 4;
  const int m0 = m * 16;
  const int j  = c * 16 + lr;        // hidden unit
  const int grow = w * 1024 + j;     // W_hh row (gate = w)

  __shared__ float smix[16][512];      // 32 KB
  __shared__ f16 hstage[16 * 1040];    // 33.3 KB, padded + XOR swizzle
  __shared__ float ldsRZ[2][16][16];   // 2 KB
  __shared__ f16 ldsH[16 * 16];        // 512 B
  __shared__ float ldsO[2][16 * 16];   // 2 KB, parity double-buffer
  __shared__ int ldsTok;

  if (tid == 0) ldsTok = 0;
  for (int i = tid; i < 2048; i += 192) {
    const int row = i >> 7;
    const int col = (i & 127) * 4;
    *(float4*)&smix[row][col] = *(const float4*)&mixp[(m0 + row) * 512 + col];
  }

  // W_hh rows as fp16 B-fragments, VGPR-resident.
  f16x8 bf[32];
#pragma unroll
  for (int kc = 0; kc < 32; ++kc) {
    const float* s = &Whh[(size_t)grow * 1024 + kc * 32 + lk];
    float4 v0 = *(const float4*)(s);
    float4 v1 = *(const float4*)(s + 4);
    f16x8 hv;
    hv[0] = v0.x; hv[1] = v0.y; hv[2] = v0.z; hv[3] = v0.w;
    hv[4] = v1.x; hv[5] = v1.y; hv[6] = v1.z; hv[7] = v1.w;
    bf[kc] = hv;
  }
  const float bhw = bhh[grow];
  float bi0 = 0.f, bi1 = 0.f, bi2 = 0.f;
  if (w == 2) { bi0 = bih[j]; bi1 = bih[1024 + j]; bi2 = bih[2048 + j]; }

  float hprev[4] = {0.f, 0.f, 0.f, 0.f};
  int* myflags = &flags[m * 64];
  int* epochp  = &flags[512 + m * 32];   // own 128B line per group

  __syncthreads();  // smix/ldsTok ready

  // producer prologue: xW(0) + mix(0)
  float xr[4], xz[4], xn[4], mt[4];
  if (w == 2) {
#pragma unroll
    for (int r = 0; r < 4; ++r) {
      const int b = m0 + rrow + r;
      xr[r] = (float)__builtin_nontemporal_load(&xw[(size_t)(0 * 64 + b) * 1024 + j]);
      xz[r] = (float)__builtin_nontemporal_load(&xw[(size_t)(1 * 64 + b) * 1024 + j]);
      xn[r] = (float)__builtin_nontemporal_load(&xw[(size_t)(2 * 64 + b) * 1024 + j]);
      mt[r] = smix[rrow + r][0];
    }
  }

  for (int t = 0; t < NT; ++t) {
    if (t > 0 && w < 2) {
      if (c == 0) {
        if (w == 0) {
          // hub: sole poller of the 64 producer flags
          while (__hip_atomic_load(&myflags[lane], __ATOMIC_RELAXED,
                                   __HIP_MEMORY_SCOPE_AGENT) < t) {}
          __builtin_amdgcn_sched_barrier(0);
          if (lane == 0)
            __hip_atomic_store(epochp, t, __ATOMIC_RELAXED, __HIP_MEMORY_SCOPE_AGENT);
          *(volatile int*)&ldsTok = t;
        } else {
          while (*(volatile int*)&ldsTok < t) {}
        }
      } else {
        // everyone else: read-only poll of the epoch word
        while (__hip_atomic_load(epochp, __ATOMIC_RELAXED,
                                 __HIP_MEMORY_SCOPE_AGENT) < t) {}
      }
      // stage our 64-chunk half (coalesced), LLC-direct
      const f16* hsrc = hbuf + (size_t)(t & 1) * (64 * 1024) + (size_t)m0 * 1024;
      f16x8 v[16];
#pragma unroll
      for (int i = 0; i < 16; ++i) {
        const int row = 2 * (i & 7) + (lane >> 5);
        const int ch  = w * 64 + (i >> 3) * 32 + (lane & 31);
        const f16* p = hsrc + row * 1024 + ch * 8;
        asm volatile("global_load_dwordx4 %0, %1, off sc0 sc1"
                     : "=v"(v[i]) : "v"(p));
      }
      if (w == 1) {
        // out(t-1): safe to read ldsO — epoch>=t implies own wave2 wrote it.
        // Issued AFTER the 16 loads so vmcnt(1) waits loads, store flies.
        f32x4 ov = *(const f32x4*)&ldsO[(t - 1) & 1][(lane >> 2) * 16 + (lane & 3) * 4];
        float* pa = out + ((size_t)(m0 + (lane >> 2)) * 512 + (t - 1)) * 1024 + c * 16 + (lane & 3) * 4;
        asm volatile("global_store_dwordx4 %0, %1, off nt"
                     :: "v"(pa), "v"(ov) : "memory");
        asm volatile("s_waitcnt vmcnt(1)" ::: "memory");
      } else {
        asm volatile("s_waitcnt vmcnt(0)" ::: "memory");
      }
#pragma unroll
      for (int i = 0; i < 16; ++i) {
        asm volatile("" : "+v"(v[i]));
        const int row = 2 * (i & 7) + (lane >> 5);
        const int ch  = w * 64 + (i >> 3) * 32 + (lane & 31);
        *(f16x8*)&hstage[row * 1040 + ((ch ^ (row & 7)) * 8)] = v[i];
      }
    }
    __syncthreads();  // B_stage
    f32x4 acc = {0.f, 0.f, 0.f, 0.f};
    if (t > 0) {
      f32x4 a0 = {0,0,0,0}, a1 = {0,0,0,0}, a2 = {0,0,0,0}, a3 = {0,0,0,0};
#pragma unroll
      for (int kc = 0; kc < 32; kc += 4) {
        f16x8 h0 = *(const f16x8*)&hstage[lr * 1040 + ((((kc + 0) * 4 + q) ^ (lr & 7)) * 8)];
        f16x8 h1 = *(const f16x8*)&hstage[lr * 1040 + ((((kc + 1) * 4 + q) ^ (lr & 7)) * 8)];
        f16x8 h2 = *(const f16x8*)&hstage[lr * 1040 + ((((kc + 2) * 4 + q) ^ (lr & 7)) * 8)];
        f16x8 h3 = *(const f16x8*)&hstage[lr * 1040 + ((((kc + 3) * 4 + q) ^ (lr & 7)) * 8)];
        a0 = __builtin_amdgcn_mfma_f32_16x16x32_f16(h0, bf[kc + 0], a0, 0, 0, 0);
        a1 = __builtin_amdgcn_mfma_f32_16x16x32_f16(h1, bf[kc + 1], a1, 0, 0, 0);
        a2 = __builtin_amdgcn_mfma_f32_16x16x32_f16(h2, bf[kc + 2], a2, 0, 0, 0);
        a3 = __builtin_amdgcn_mfma_f32_16x16x32_f16(h3, bf[kc + 3], a3, 0, 0, 0);
      }
      acc = (a0 + a1) + (a2 + a3);
    }
    if (w < 2) {
#pragma unroll
      for (int r = 0; r < 4; ++r) ldsRZ[w][rrow + r][lr] = acc[r] + bhw;
    }
    __syncthreads();  // B_rz
    if (w == 2) {
      float* lo = &ldsO[t & 1][0];
#pragma unroll
      for (int r = 0; r < 4; ++r) {
        const int row = rrow + r;
        const float hr = ldsRZ[0][row][lr];
        const float hz = ldsRZ[1][row][lr];
        const float hn = acc[r] + bhw;
        const float rg = sigm(xr[r] + bi0 + hr);
        const float zg = sigm(xz[r] + bi1 + hz);
        const float ng = tanh_fast(xn[r] + bi2 + rg * hn);
        const float hnew = (1.f - zg) * ng + zg * hprev[r];
        const float hm = mt[r] * hnew + (1.f - mt[r]) * hprev[r];
        hprev[r] = hm;
        ldsH[row * 16 + lr] = (f16)hm;
        lo[row * 16 + lr] = hm;
      }
      // same-wave LDS bounce (no barrier): ds_writes then lane<32 ds_read
      if (lane < 32) {
        f16x8 hv = *(const f16x8*)&ldsH[(lane >> 1) * 16 + (lane & 1) * 8];
        f16* p = hbuf + (size_t)((t + 1) & 1) * (64 * 1024)
               + (size_t)(m0 + (lane >> 1)) * 1024 + c * 16 + (lane & 1) * 8;
        asm volatile("global_store_dwordx4 %0, %1, off sc0 sc1"
                     :: "v"(p), "v"(hv) : "memory");
      }
      // order: h-store ack'd AND ldsO/ldsH writes retired before flag
      asm volatile("s_waitcnt vmcnt(0) lgkmcnt(0)" ::: "memory");
      if (lane == 0)
        __hip_atomic_store(&myflags[c], t + 1, __ATOMIC_RELAXED, __HIP_MEMORY_SCOPE_AGENT);
      // off-path: next-step xW prefetch
      const int tn = (t + 1 < NT) ? t + 1 : NT - 1;
#pragma unroll
      for (int r = 0; r < 4; ++r) {
        const int b = m0 + rrow + r;
        xr[r] = (float)__builtin_nontemporal_load(&xw[(size_t)((tn * 3 + 0) * 64 + b) * 1024 + j]);
        xz[r] = (float)__builtin_nontemporal_load(&xw[(size_t)((tn * 3 + 1) * 64 + b) * 1024 + j]);
        xn[r] = (float)__builtin_nontemporal_load(&xw[(size_t)((tn * 3 + 2) * 64 + b) * 1024 + j]);
        mt[r] = smix[rrow + r][tn];
      }
    }
  }
  __syncthreads();  // ldsO[1] (t=511) final
  if (w == 1) {
    const int row = lane >> 2, part = lane & 3;
    f32x4 ov = *(const f32x4*)&ldsO[1][row * 16 + part * 4];
    float* p1 = out + ((size_t)(m0 + row) * 512 + 511) * 1024 + c * 16 + part * 4;
    float* p2 = out + (size_t)64 * 512 * 1024 + (size_t)(m0 + row) * 1024 + c * 16 + part * 4;
    __builtin_nontemporal_store(ov, (f32x4*)p1);
    __builtin_nontemporal_store(ov, (f32x4*)p2);
  }
}

// ---------------------------------------------------------------------------
extern "C" void kernel_launch(void* const* d_in, const int* in_sizes, int n_in,
                              void* d_out, int out_size, void* d_ws, size_t ws_size,
                              hipStream_t stream) {
  const float* x    = (const float*)d_in[0];
  const float* mixp = (const float*)d_in[1];
  const float* Wih  = (const float*)d_in[2];
  const float* Whh  = (const float*)d_in[3];
  const float* bih  = (const float*)d_in[4];
  const float* bhh  = (const float*)d_in[5];
  float* out = (float*)d_out;

  const size_t XW_BYTES = (size_t)512 * 3 * 64 * 1024 * sizeof(f16);  // 201326592
  f16* xw    = (f16*)d_ws;
  f16* hbuf  = (f16*)((char*)d_ws + XW_BYTES);
  int* flags = (int*)((char*)d_ws + XW_BYTES + (size_t)2 * 64 * 1024 * sizeof(f16));

  hipMemsetAsync(flags, 0, 4096, stream);  // prod flags + epoch words

  dim3 gg(24, 256);
  gemm_xw<<<gg, 256, 0, stream>>>(x, Wih, xw);

  dim3 gr(64, 4);
  recur<<<gr, 192, 0, stream>>>(xw, mixp, Whh, bih, bhh, out, hbuf, flags);
}